// Round 1
// baseline (198.899 us; speedup 1.0000x reference)
//
#include <hip/hip_runtime.h>
#include <hip/hip_bf16.h>

// Problem: B=2, S=2048, D=256, H=8.
// out[b,h,s,:] = sum_{t<=s} exp( max(d2(s,t),0) / (2*gamma_h - 1e-6) ) * V[b,t,:]
// d2(s,t) = |Q_s|^2 + |K_t|^2 - 2 Q_s.K_t ; Q=p@Wq, K=p@Wk, V=e@Wv.
// Heads with equal gamma produce identical outputs -> dedupe by representative.

#define BB   2
#define SS   2048
#define DD   256
#define HH   8
#define BSR  (BB*SS)        // 4096 rows
#define TSPLIT 4

typedef __bf16 bf16_t;
typedef __bf16 bf16x8 __attribute__((ext_vector_type(8)));
typedef float  f32x4  __attribute__((ext_vector_type(4)));

static __device__ __forceinline__ f32x4 mfma16(bf16x8 a, bf16x8 b, f32x4 c) {
    return __builtin_amdgcn_mfma_f32_16x16x32_bf16(a, b, c, 0, 0, 0);
}

// ---------------------------------------------------------------------------
// K1: QKV projection (fp32), emit Qh/Ql,Kh/Kl (bf16 hi/lo split, row-major),
//     V transposed as Vt[b][d][t] (bf16), and q2/k2 (fp32 row norms).
// Grid: 256 blocks x 256 threads; each block owns 16 consecutive rows.
// ---------------------------------------------------------------------------
__global__ __launch_bounds__(256) void att_qkv_prep(
    const float* __restrict__ p, const float* __restrict__ e,
    const float* __restrict__ Wq, const float* __restrict__ Wk,
    const float* __restrict__ Wv,
    bf16_t* __restrict__ Qh, bf16_t* __restrict__ Ql,
    bf16_t* __restrict__ Kh, bf16_t* __restrict__ Kl,
    bf16_t* __restrict__ Vt, float* __restrict__ q2, float* __restrict__ k2)
{
    __shared__ float pt[256][20];   // p transposed [k][r], pad 20 for b128 reads
    __shared__ float et[256][20];
    __shared__ float red[2][16][4];

    const int tid  = threadIdx.x;
    const int row0 = blockIdx.x * 16;

    for (int r = 0; r < 16; ++r) {
        pt[tid][r] = p[(size_t)(row0 + r) * DD + tid];
        et[tid][r] = e[(size_t)(row0 + r) * DD + tid];
    }
    __syncthreads();

    float aq[16], ak[16], av[16];
#pragma unroll
    for (int r = 0; r < 16; ++r) { aq[r] = 0.f; ak[r] = 0.f; av[r] = 0.f; }

    for (int k = 0; k < 256; ++k) {
        const float wq = Wq[k * DD + tid];
        const float wk = Wk[k * DD + tid];
        const float wv = Wv[k * DD + tid];
#pragma unroll
        for (int c4 = 0; c4 < 4; ++c4) {
            const float4 pv = *(const float4*)&pt[k][c4 * 4];
            const float4 ev = *(const float4*)&et[k][c4 * 4];
            const float pa[4] = {pv.x, pv.y, pv.z, pv.w};
            const float ea[4] = {ev.x, ev.y, ev.z, ev.w};
#pragma unroll
            for (int j = 0; j < 4; ++j) {
                aq[c4 * 4 + j] = fmaf(pa[j], wq, aq[c4 * 4 + j]);
                ak[c4 * 4 + j] = fmaf(pa[j], wk, ak[c4 * 4 + j]);
                av[c4 * 4 + j] = fmaf(ea[j], wv, av[c4 * 4 + j]);
            }
        }
    }

    // Store Q/K hi-lo bf16 splits, pack V row for transposed store.
    unsigned int vw[8];
#pragma unroll
    for (int r = 0; r < 16; ++r) {
        const size_t grow = (size_t)(row0 + r);
        const float q = aq[r], kk = ak[r], v = av[r];
        const bf16_t qh = (bf16_t)q;  const bf16_t ql = (bf16_t)(q - (float)qh);
        const bf16_t kh = (bf16_t)kk; const bf16_t kl = (bf16_t)(kk - (float)kh);
        Qh[grow * DD + tid] = qh;  Ql[grow * DD + tid] = ql;
        Kh[grow * DD + tid] = kh;  Kl[grow * DD + tid] = kl;
        const unsigned short vb = __builtin_bit_cast(unsigned short, (bf16_t)v);
        if ((r & 1) == 0) vw[r >> 1] = vb;
        else              vw[r >> 1] |= ((unsigned int)vb) << 16;
    }
    {
        const int bb  = row0 >> 11;        // row0 / 2048
        const int t0v = row0 & 2047;
        bf16_t* dst = Vt + (size_t)bb * DD * SS + (size_t)tid * SS + t0v;
        uint4 u0; u0.x = vw[0]; u0.y = vw[1]; u0.z = vw[2]; u0.w = vw[3];
        uint4 u1; u1.x = vw[4]; u1.y = vw[5]; u1.z = vw[6]; u1.w = vw[7];
        *(uint4*)dst       = u0;
        *((uint4*)dst + 1) = u1;
    }

    // q2/k2: block-wide reduction over the 256 columns.
    const int wv_ = tid >> 6, ln = tid & 63;
#pragma unroll
    for (int r = 0; r < 16; ++r) {
        float vq = aq[r] * aq[r];
        float vk = ak[r] * ak[r];
#pragma unroll
        for (int off = 32; off >= 1; off >>= 1) {
            vq += __shfl_xor(vq, off);
            vk += __shfl_xor(vk, off);
        }
        if (ln == 0) { red[0][r][wv_] = vq; red[1][r][wv_] = vk; }
    }
    __syncthreads();
    if (tid < 16) {
        q2[row0 + tid] = red[0][tid][0] + red[0][tid][1] + red[0][tid][2] + red[0][tid][3];
        k2[row0 + tid] = red[1][tid][0] + red[1][tid][1] + red[1][tid][2] + red[1][tid][3];
    }
}

// ---------------------------------------------------------------------------
// K2: flash-style causal pass. Block = 256 thr (4 waves), owns 32 s-rows x
// full D=256 for one representative head set; grid (S/32, TSPLIT, B).
// Scores: bf16x3 split MFMA (fp32-accurate dot). PV: bf16 MFMA.
// Partial results accumulated into zeroed d_out via fp32 atomics.
// ---------------------------------------------------------------------------
__global__ __launch_bounds__(256) void att_flash(
    const bf16_t* __restrict__ Qh, const bf16_t* __restrict__ Ql,
    const bf16_t* __restrict__ Kh, const bf16_t* __restrict__ Kl,
    const bf16_t* __restrict__ Vt, const float* __restrict__ q2,
    const float* __restrict__ k2, const float* __restrict__ gamma,
    float* __restrict__ out)
{
    __shared__ bf16_t qs[2][32][264];  // +8 pad: b128 frag reads 2-way max
    __shared__ bf16_t Pb[2][32][72];   // P double buffer, stride 72 (144B rows)

    const int tid   = threadIdx.x;
    const int st    = blockIdx.x;
    const int split = blockIdx.y;
    const int b     = blockIdx.z;
    const int wave  = tid >> 6;
    const int lane  = tid & 63;
    const int m16   = lane & 15;
    const int quad  = lane >> 4;
    const int s0    = st * 32;

    // Stage Q tile (hi & lo) into LDS.
    for (int cc = tid; cc < 32 * 32; cc += 256) {
        const int row = cc >> 5, ch = cc & 31;
        const size_t goff = ((size_t)(b * SS + s0 + row)) * DD + ch * 8;
        *(uint4*)&qs[0][row][ch * 8] = *(const uint4*)(Qh + goff);
        *(uint4*)&qs[1][row][ch * 8] = *(const uint4*)(Ql + goff);
    }
    __syncthreads();

    float g[8];
#pragma unroll
    for (int h = 0; h < 8; ++h) g[h] = gamma[h];

    const int n_tiles = (s0 + 31) / 64 + 1;   // t-tiles of 64 with t0 <= s0+31
    int pb = 0;

    for (int h = 0; h < HH; ++h) {
        int rep = 0;
        while (g[rep] != g[h]) ++rep;
        if (rep != h) continue;               // duplicate head: copy kernel fills it
        const float cexp = 1.0f / (2.0f * g[h] - 1e-6f);

        f32x4 O[2][4];
#pragma unroll
        for (int mt = 0; mt < 2; ++mt)
#pragma unroll
            for (int nt = 0; nt < 4; ++nt)
                O[mt][nt] = f32x4{0.f, 0.f, 0.f, 0.f};

        for (int ti = split; ti < n_tiles; ti += TSPLIT) {
            const int t0 = ti * 64;
            const int tg = t0 + wave * 16 + m16;   // this lane's t column

            // ---- scores: S = Qh.Kh + Ql.Kh + Qh.Kl (fp32 acc) ----
            f32x4 acc0 = f32x4{0.f, 0.f, 0.f, 0.f};
            f32x4 acc1 = f32x4{0.f, 0.f, 0.f, 0.f};
            const bf16_t* khp = Kh + ((size_t)(b * SS + tg)) * DD + quad * 8;
            const bf16_t* klp = Kl + ((size_t)(b * SS + tg)) * DD + quad * 8;
#pragma unroll
            for (int kc = 0; kc < 8; ++kc) {
                const bf16x8 bh  = *(const bf16x8*)(khp + kc * 32);
                const bf16x8 bl  = *(const bf16x8*)(klp + kc * 32);
                const bf16x8 a0h = *(const bf16x8*)&qs[0][m16][kc * 32 + quad * 8];
                const bf16x8 a0l = *(const bf16x8*)&qs[1][m16][kc * 32 + quad * 8];
                const bf16x8 a1h = *(const bf16x8*)&qs[0][m16 + 16][kc * 32 + quad * 8];
                const bf16x8 a1l = *(const bf16x8*)&qs[1][m16 + 16][kc * 32 + quad * 8];
                acc0 = mfma16(a0h, bh, acc0);
                acc0 = mfma16(a0l, bh, acc0);
                acc0 = mfma16(a0h, bl, acc0);
                acc1 = mfma16(a1h, bh, acc1);
                acc1 = mfma16(a1l, bh, acc1);
                acc1 = mfma16(a1h, bl, acc1);
            }

            const float k2v = k2[b * SS + tg];
#pragma unroll
            for (int mt = 0; mt < 2; ++mt) {
#pragma unroll
                for (int r = 0; r < 4; ++r) {
                    const int sl = mt * 16 + quad * 4 + r;
                    const int sg = s0 + sl;
                    const float dotv = mt ? acc1[r] : acc0[r];
                    float d2 = q2[b * SS + sg] + k2v - 2.0f * dotv;
                    d2 = fmaxf(d2, 0.0f);
                    const float wgt = (tg <= sg) ? __expf(cexp * d2) : 0.0f;
                    Pb[pb][sl][wave * 16 + m16] = (bf16_t)wgt;
                }
            }
            __syncthreads();

            // ---- PV: O += P @ V (bf16 MFMA, Vt gives contiguous B-frags) ----
#pragma unroll
            for (int kc2 = 0; kc2 < 2; ++kc2) {
                const bf16x8 pa0 = *(const bf16x8*)&Pb[pb][m16][kc2 * 32 + quad * 8];
                const bf16x8 pa1 = *(const bf16x8*)&Pb[pb][m16 + 16][kc2 * 32 + quad * 8];
#pragma unroll
                for (int nt = 0; nt < 4; ++nt) {
                    const int dcol = wave * 64 + nt * 16 + m16;
                    const bf16x8 bv = *(const bf16x8*)(
                        Vt + (size_t)b * DD * SS + (size_t)dcol * SS + t0 + kc2 * 32 + quad * 8);
                    O[0][nt] = mfma16(pa0, bv, O[0][nt]);
                    O[1][nt] = mfma16(pa1, bv, O[1][nt]);
                }
            }
            pb ^= 1;
        }

        // ---- accumulate split partials into out[b][h] ----
#pragma unroll
        for (int mt = 0; mt < 2; ++mt)
#pragma unroll
            for (int nt = 0; nt < 4; ++nt)
#pragma unroll
                for (int r = 0; r < 4; ++r) {
                    const int sl   = mt * 16 + quad * 4 + r;
                    const int dcol = wave * 64 + nt * 16 + m16;
                    atomicAdd(out + (((size_t)b * HH + h) * SS + (s0 + sl)) * DD + dcol,
                              O[mt][nt][r]);
                }
    }
}

// ---------------------------------------------------------------------------
// K3: replicate representative-head outputs to duplicate-gamma heads.
// ---------------------------------------------------------------------------
__global__ __launch_bounds__(256) void att_copy_heads(
    const float* __restrict__ gamma, float* __restrict__ out)
{
    const int idx = blockIdx.x * 256 + threadIdx.x;   // float4 index, 2^21 total
    const int h = (idx >> 17) & 7;                    // 64*2048 float4 per (b,h)
    const float gh = gamma[h];
    int rep = 0;
    while (gamma[rep] != gh) ++rep;
    if (rep == h) return;
    float4* o4 = (float4*)out;
    o4[idx] = o4[idx - ((size_t)(h - rep) << 17)];
}

extern "C" void kernel_launch(void* const* d_in, const int* in_sizes, int n_in,
                              void* d_out, int out_size, void* d_ws, size_t ws_size,
                              hipStream_t stream) {
    (void)in_sizes; (void)n_in; (void)out_size; (void)ws_size;
    // inputs: 0=x (unused), 1=e, 2=p, 3=W_q, 4=W_k, 5=W_v, 6=gamma
    const float* e     = (const float*)d_in[1];
    const float* p     = (const float*)d_in[2];
    const float* Wq    = (const float*)d_in[3];
    const float* Wk    = (const float*)d_in[4];
    const float* Wv    = (const float*)d_in[5];
    const float* gamma = (const float*)d_in[6];

    const size_t NROW = (size_t)BSR * DD;   // 1048576 elements
    bf16_t* Qh = (bf16_t*)d_ws;
    bf16_t* Ql = Qh + NROW;
    bf16_t* Kh = Ql + NROW;
    bf16_t* Kl = Kh + NROW;
    bf16_t* Vt = Kl + NROW;                 // [B][D][S]
    float*  q2 = (float*)(Vt + NROW);
    float*  k2 = q2 + BSR;

    float* out = (float*)d_out;

    hipMemsetAsync(d_out, 0, (size_t)BB * HH * SS * DD * sizeof(float), stream);

    att_qkv_prep<<<dim3(BSR / 16), dim3(256), 0, stream>>>(
        p, e, Wq, Wk, Wv, Qh, Ql, Kh, Kl, Vt, q2, k2);

    att_flash<<<dim3(SS / 32, TSPLIT, BB), dim3(256), 0, stream>>>(
        Qh, Ql, Kh, Kl, Vt, q2, k2, gamma, out);

    att_copy_heads<<<dim3((BB * HH * SS * DD / 4) / 256), dim3(256), 0, stream>>>(
        gamma, out);
}

// Round 2
// 179.767 us; speedup vs baseline: 1.1064x; 1.1064x over previous
//
#include <hip/hip_runtime.h>
#include <hip/hip_bf16.h>

// Problem: B=2, S=2048, D=256, H=8.
// out[b,h,s,:] = sum_{t<=s} exp( max(d2(s,t),0) / (2*gamma_h - 1e-6) ) * V[b,t,:]
// d2(s,t) = |Q_s|^2 + |K_t|^2 - 2 Q_s.K_t ; Q=p@Wq, K=p@Wk, V=e@Wv.
// Heads with equal gamma produce identical outputs -> dedupe by representative.

#define BB   2
#define SS   2048
#define DD   256
#define HH   8
#define BSR  (BB*SS)        // 4096 rows
#define TSPLIT 4

typedef __bf16 bf16_t;
typedef __bf16 bf16x8 __attribute__((ext_vector_type(8)));
typedef float  f32x4  __attribute__((ext_vector_type(4)));

static __device__ __forceinline__ f32x4 mfma16(bf16x8 a, bf16x8 b, f32x4 c) {
    return __builtin_amdgcn_mfma_f32_16x16x32_bf16(a, b, c, 0, 0, 0);
}

// ---------------------------------------------------------------------------
// K0: W transpose + bf16 hi/lo split. Wt[n][k] = W[k][n] so MFMA B-frags
// (lane = col n, k contiguous) read 16B straight runs. 48 blocks.
// ---------------------------------------------------------------------------
__global__ __launch_bounds__(256) void att_wtrans(
    const float* __restrict__ Wq, const float* __restrict__ Wk,
    const float* __restrict__ Wv,
    bf16_t* __restrict__ Wqt_h, bf16_t* __restrict__ Wqt_l,
    bf16_t* __restrict__ Wkt_h, bf16_t* __restrict__ Wkt_l,
    bf16_t* __restrict__ Wvt)
{
    __shared__ float tile[64][65];
    const int tid = threadIdx.x;
    const int mat = blockIdx.x >> 4;        // 0=Wq 1=Wk 2=Wv
    const int tl  = blockIdx.x & 15;
    const int tr  = (tl >> 2) * 64, tc = (tl & 3) * 64;
    const float* W = (mat == 0) ? Wq : ((mat == 1) ? Wk : Wv);
    const int c = tid & 63, r0 = tid >> 6;

#pragma unroll
    for (int i = 0; i < 16; ++i)
        tile[r0 + 4 * i][c] = W[(size_t)(tr + r0 + 4 * i) * DD + tc + c];
    __syncthreads();

#pragma unroll
    for (int i = 0; i < 16; ++i) {
        const int nr = r0 + 4 * i;
        const float v = tile[c][nr];            // W[tr+c][tc+nr]
        const size_t oidx = (size_t)(tc + nr) * DD + tr + c;
        if (mat == 0) {
            const bf16_t h = (bf16_t)v;
            Wqt_h[oidx] = h; Wqt_l[oidx] = (bf16_t)(v - (float)h);
        } else if (mat == 1) {
            const bf16_t h = (bf16_t)v;
            Wkt_h[oidx] = h; Wkt_l[oidx] = (bf16_t)(v - (float)h);
        } else {
            Wvt[oidx] = (bf16_t)v;
        }
    }
}

// ---------------------------------------------------------------------------
// K1: fused QKV projection via MFMA. Block = 512 thr (8 waves), 16 rows,
// wave w owns cols [w*32, w*32+32). A-frags: fp32 p/e loaded from global
// (quad-broadcast, L1-hot) and hi/lo-split in-register. Q/K use the bf16x3
// split (fp32-class accuracy); V is single bf16. Epilogue: hi/lo stores,
// exact fp32 q2/k2 row norms, LDS-transposed Vt[b][d][t] write.
// ---------------------------------------------------------------------------
__global__ __launch_bounds__(512) void att_gemm_qkv(
    const float* __restrict__ p, const float* __restrict__ e,
    const bf16_t* __restrict__ Wqt_h, const bf16_t* __restrict__ Wqt_l,
    const bf16_t* __restrict__ Wkt_h, const bf16_t* __restrict__ Wkt_l,
    const bf16_t* __restrict__ Wvt,
    bf16_t* __restrict__ Qh, bf16_t* __restrict__ Ql,
    bf16_t* __restrict__ Kh, bf16_t* __restrict__ Kl,
    bf16_t* __restrict__ Vt, float* __restrict__ q2, float* __restrict__ k2)
{
    __shared__ float redq[16][8];
    __shared__ float redk[16][8];
    __shared__ bf16_t vts[256][16];

    const int tid  = threadIdx.x;
    const int w    = tid >> 6;
    const int lane = tid & 63;
    const int m16  = lane & 15;
    const int quad = lane >> 4;
    const int row0 = blockIdx.x * 16;
    const int arow = row0 + m16;            // this lane's A row

    f32x4 aQ[2], aK[2], aV[2];
#pragma unroll
    for (int nt = 0; nt < 2; ++nt) {
        aQ[nt] = f32x4{0.f, 0.f, 0.f, 0.f};
        aK[nt] = f32x4{0.f, 0.f, 0.f, 0.f};
        aV[nt] = f32x4{0.f, 0.f, 0.f, 0.f};
    }

#pragma unroll 2
    for (int kc = 0; kc < 8; ++kc) {
        const float* pp = p + (size_t)arow * DD + kc * 32 + quad * 8;
        const float* ep = e + (size_t)arow * DD + kc * 32 + quad * 8;
        const float4 p0 = *(const float4*)pp;
        const float4 p1 = *(const float4*)(pp + 4);
        const float4 e0 = *(const float4*)ep;
        const float4 e1 = *(const float4*)(ep + 4);
        const float pa[8] = {p0.x, p0.y, p0.z, p0.w, p1.x, p1.y, p1.z, p1.w};
        const float ea[8] = {e0.x, e0.y, e0.z, e0.w, e1.x, e1.y, e1.z, e1.w};
        bf16x8 aph, apl, aeb;
#pragma unroll
        for (int j = 0; j < 8; ++j) {
            const bf16_t h = (bf16_t)pa[j];
            aph[j] = h;
            apl[j] = (bf16_t)(pa[j] - (float)h);
            aeb[j] = (bf16_t)ea[j];
        }
#pragma unroll
        for (int nt = 0; nt < 2; ++nt) {
            const int n = w * 32 + nt * 16 + m16;
            const size_t wo = (size_t)n * DD + kc * 32 + quad * 8;
            const bf16x8 bqh = *(const bf16x8*)(Wqt_h + wo);
            const bf16x8 bql = *(const bf16x8*)(Wqt_l + wo);
            const bf16x8 bkh = *(const bf16x8*)(Wkt_h + wo);
            const bf16x8 bkl = *(const bf16x8*)(Wkt_l + wo);
            const bf16x8 bv  = *(const bf16x8*)(Wvt + wo);
            aQ[nt] = mfma16(aph, bqh, aQ[nt]);
            aQ[nt] = mfma16(apl, bqh, aQ[nt]);
            aQ[nt] = mfma16(aph, bql, aQ[nt]);
            aK[nt] = mfma16(aph, bkh, aK[nt]);
            aK[nt] = mfma16(apl, bkh, aK[nt]);
            aK[nt] = mfma16(aph, bkl, aK[nt]);
            aV[nt] = mfma16(aeb, bv, aV[nt]);
        }
    }

    // Epilogue: stores + row-norm partials + V transpose staging.
    float sq[4] = {0.f, 0.f, 0.f, 0.f}, sk[4] = {0.f, 0.f, 0.f, 0.f};
#pragma unroll
    for (int nt = 0; nt < 2; ++nt) {
        const int col = w * 32 + nt * 16 + m16;
#pragma unroll
        for (int r = 0; r < 4; ++r) {
            const int rl = quad * 4 + r;          // C/D row = quad*4+reg
            const size_t go = (size_t)(row0 + rl) * DD + col;
            const float qv = aQ[nt][r], kv = aK[nt][r], vv = aV[nt][r];
            const bf16_t qh_ = (bf16_t)qv; const bf16_t ql_ = (bf16_t)(qv - (float)qh_);
            const bf16_t kh_ = (bf16_t)kv; const bf16_t kl_ = (bf16_t)(kv - (float)kh_);
            Qh[go] = qh_; Ql[go] = ql_;
            Kh[go] = kh_; Kl[go] = kl_;
            sq[r] += qv * qv; sk[r] += kv * kv;
            vts[col][rl] = (bf16_t)vv;
        }
    }

#pragma unroll
    for (int r = 0; r < 4; ++r) {
        float vq = sq[r], vk = sk[r];
#pragma unroll
        for (int off = 8; off >= 1; off >>= 1) {
            vq += __shfl_xor(vq, off);
            vk += __shfl_xor(vk, off);
        }
        if (m16 == 0) { redq[quad * 4 + r][w] = vq; redk[quad * 4 + r][w] = vk; }
    }
    __syncthreads();

    if (tid < 16) {
        float aq2 = 0.f, ak2 = 0.f;
#pragma unroll
        for (int ww = 0; ww < 8; ++ww) { aq2 += redq[tid][ww]; ak2 += redk[tid][ww]; }
        q2[row0 + tid] = aq2;
        k2[row0 + tid] = ak2;
    }
    if (tid < 256) {
        const int bb2 = row0 >> 11, t0v = row0 & 2047;
        bf16_t* dst = Vt + ((size_t)bb2 * DD + tid) * SS + t0v;
        *(uint4*)dst       = *(const uint4*)&vts[tid][0];
        *((uint4*)dst + 1) = *(const uint4*)&vts[tid][8];
    }
}

// ---------------------------------------------------------------------------
// K2: flash-style causal pass. Block = 256 thr (4 waves), 32 s-rows x D=256;
// grid (S/32, TSPLIT, B). Q hi/lo fragments live in REGISTERS (loaded once,
// reused across all tiles & heads) -> per-tile LDS traffic is P only.
// Scores: bf16x3 split MFMA (fp32-accurate dot). PV: bf16 MFMA.
// Partial results accumulated into zeroed d_out via fp32 atomics.
// ---------------------------------------------------------------------------
__global__ __launch_bounds__(256, 2) void att_flash(
    const bf16_t* __restrict__ Qh, const bf16_t* __restrict__ Ql,
    const bf16_t* __restrict__ Kh, const bf16_t* __restrict__ Kl,
    const bf16_t* __restrict__ Vt, const float* __restrict__ q2,
    const float* __restrict__ k2, const float* __restrict__ gamma,
    float* __restrict__ out)
{
    __shared__ bf16_t Pb[2][32][72];   // P double buffer, stride 72 (144B rows)

    const int tid   = threadIdx.x;
    const int st    = blockIdx.x;
    const int split = blockIdx.y;
    const int b     = blockIdx.z;
    const int wave  = tid >> 6;
    const int lane  = tid & 63;
    const int m16   = lane & 15;
    const int quad  = lane >> 4;
    const int s0    = st * 32;

    // Q fragments -> registers (16 hi + 16 lo bf16x8 = 128 VGPRs).
    bf16x8 aQh[2][8], aQl[2][8];
#pragma unroll
    for (int mt = 0; mt < 2; ++mt)
#pragma unroll
        for (int kc = 0; kc < 8; ++kc) {
            const size_t base =
                ((size_t)(b * SS + s0 + mt * 16 + m16)) * DD + kc * 32 + quad * 8;
            aQh[mt][kc] = *(const bf16x8*)(Qh + base);
            aQl[mt][kc] = *(const bf16x8*)(Ql + base);
        }

    // q2 for this lane's output rows (fixed for whole kernel).
    float q2r[2][4];
#pragma unroll
    for (int mt = 0; mt < 2; ++mt)
#pragma unroll
        for (int r = 0; r < 4; ++r)
            q2r[mt][r] = q2[b * SS + s0 + mt * 16 + quad * 4 + r];

    float g[8];
#pragma unroll
    for (int h = 0; h < 8; ++h) g[h] = gamma[h];

    const int n_tiles = (s0 + 31) / 64 + 1;   // t-tiles of 64 with t0 <= s0+31
    int pb = 0;

    for (int h = 0; h < HH; ++h) {
        int rep = 0;
        while (g[rep] != g[h]) ++rep;
        if (rep != h) continue;               // duplicate head: copy kernel fills it
        const float cexp = 1.0f / (2.0f * g[h] - 1e-6f);

        f32x4 O[2][4];
#pragma unroll
        for (int mt = 0; mt < 2; ++mt)
#pragma unroll
            for (int nt = 0; nt < 4; ++nt)
                O[mt][nt] = f32x4{0.f, 0.f, 0.f, 0.f};

        for (int ti = split; ti < n_tiles; ti += TSPLIT) {
            const int t0 = ti * 64;
            const int tg = t0 + wave * 16 + m16;   // this lane's t column

            // ---- scores: S = Qh.Kh + Ql.Kh + Qh.Kl (fp32 acc) ----
            f32x4 acc0 = f32x4{0.f, 0.f, 0.f, 0.f};
            f32x4 acc1 = f32x4{0.f, 0.f, 0.f, 0.f};
            const bf16_t* khp = Kh + ((size_t)(b * SS + tg)) * DD + quad * 8;
            const bf16_t* klp = Kl + ((size_t)(b * SS + tg)) * DD + quad * 8;
#pragma unroll
            for (int kc = 0; kc < 8; ++kc) {
                const bf16x8 bh = *(const bf16x8*)(khp + kc * 32);
                const bf16x8 bl = *(const bf16x8*)(klp + kc * 32);
                acc0 = mfma16(aQh[0][kc], bh, acc0);
                acc1 = mfma16(aQh[1][kc], bh, acc1);
                acc0 = mfma16(aQl[0][kc], bh, acc0);
                acc1 = mfma16(aQl[1][kc], bh, acc1);
                acc0 = mfma16(aQh[0][kc], bl, acc0);
                acc1 = mfma16(aQh[1][kc], bl, acc1);
            }

            const float k2v = k2[b * SS + tg];
#pragma unroll
            for (int mt = 0; mt < 2; ++mt) {
#pragma unroll
                for (int r = 0; r < 4; ++r) {
                    const int sl = mt * 16 + quad * 4 + r;
                    const int sg = s0 + sl;
                    const float dotv = mt ? acc1[r] : acc0[r];
                    float d2 = q2r[mt][r] + k2v - 2.0f * dotv;
                    d2 = fmaxf(d2, 0.0f);
                    const float wgt = (tg <= sg) ? __expf(cexp * d2) : 0.0f;
                    Pb[pb][sl][wave * 16 + m16] = (bf16_t)wgt;
                }
            }
            __syncthreads();

            // ---- PV: O += P @ V (bf16 MFMA, Vt gives contiguous B-frags) ----
#pragma unroll
            for (int kc2 = 0; kc2 < 2; ++kc2) {
                const bf16x8 pa0 = *(const bf16x8*)&Pb[pb][m16][kc2 * 32 + quad * 8];
                const bf16x8 pa1 = *(const bf16x8*)&Pb[pb][m16 + 16][kc2 * 32 + quad * 8];
#pragma unroll
                for (int nt = 0; nt < 4; ++nt) {
                    const int dcol = wave * 64 + nt * 16 + m16;
                    const bf16x8 bv = *(const bf16x8*)(
                        Vt + (size_t)b * DD * SS + (size_t)dcol * SS + t0 + kc2 * 32 + quad * 8);
                    O[0][nt] = mfma16(pa0, bv, O[0][nt]);
                    O[1][nt] = mfma16(pa1, bv, O[1][nt]);
                }
            }
            pb ^= 1;
        }

        // ---- accumulate split partials into out[b][h] ----
#pragma unroll
        for (int mt = 0; mt < 2; ++mt)
#pragma unroll
            for (int nt = 0; nt < 4; ++nt)
#pragma unroll
                for (int r = 0; r < 4; ++r) {
                    const int sl   = mt * 16 + quad * 4 + r;
                    const int dcol = wave * 64 + nt * 16 + m16;
                    atomicAdd(out + (((size_t)b * HH + h) * SS + (s0 + sl)) * DD + dcol,
                              O[mt][nt][r]);
                }
    }
}

// ---------------------------------------------------------------------------
// K3: replicate representative-head outputs to duplicate-gamma heads.
// ---------------------------------------------------------------------------
__global__ __launch_bounds__(256) void att_copy_heads(
    const float* __restrict__ gamma, float* __restrict__ out)
{
    const int idx = blockIdx.x * 256 + threadIdx.x;   // float4 index, 2^21 total
    const int h = (idx >> 17) & 7;                    // 64*2048 float4 per (b,h)
    const float gh = gamma[h];
    int rep = 0;
    while (gamma[rep] != gh) ++rep;
    if (rep == h) return;
    float4* o4 = (float4*)out;
    o4[idx] = o4[idx - ((size_t)(h - rep) << 17)];
}

extern "C" void kernel_launch(void* const* d_in, const int* in_sizes, int n_in,
                              void* d_out, int out_size, void* d_ws, size_t ws_size,
                              hipStream_t stream) {
    (void)in_sizes; (void)n_in; (void)out_size; (void)ws_size;
    // inputs: 0=x (unused), 1=e, 2=p, 3=W_q, 4=W_k, 5=W_v, 6=gamma
    const float* e     = (const float*)d_in[1];
    const float* p     = (const float*)d_in[2];
    const float* Wq    = (const float*)d_in[3];
    const float* Wk    = (const float*)d_in[4];
    const float* Wv    = (const float*)d_in[5];
    const float* gamma = (const float*)d_in[6];

    const size_t NROW = (size_t)BSR * DD;   // 1048576 elements
    bf16_t* Qh = (bf16_t*)d_ws;
    bf16_t* Ql = Qh + NROW;
    bf16_t* Kh = Ql + NROW;
    bf16_t* Kl = Kh + NROW;
    bf16_t* Vt = Kl + NROW;                 // [B][D][S]
    float*  q2 = (float*)(Vt + NROW);
    float*  k2 = q2 + BSR;
    bf16_t* Wqt_h = (bf16_t*)(k2 + BSR);    // transposed weights [n][k]
    bf16_t* Wqt_l = Wqt_h + DD * DD;
    bf16_t* Wkt_h = Wqt_l + DD * DD;
    bf16_t* Wkt_l = Wkt_h + DD * DD;
    bf16_t* Wvt   = Wkt_l + DD * DD;

    float* out = (float*)d_out;

    hipMemsetAsync(d_out, 0, (size_t)BB * HH * SS * DD * sizeof(float), stream);

    att_wtrans<<<dim3(48), dim3(256), 0, stream>>>(
        Wq, Wk, Wv, Wqt_h, Wqt_l, Wkt_h, Wkt_l, Wvt);

    att_gemm_qkv<<<dim3(BSR / 16), dim3(512), 0, stream>>>(
        p, e, Wqt_h, Wqt_l, Wkt_h, Wkt_l, Wvt, Qh, Ql, Kh, Kl, Vt, q2, k2);

    att_flash<<<dim3(SS / 32, TSPLIT, BB), dim3(256), 0, stream>>>(
        Qh, Ql, Kh, Kl, Vt, q2, k2, gamma, out);

    att_copy_heads<<<dim3((BB * HH * SS * DD / 4) / 256), dim3(256), 0, stream>>>(
        gamma, out);
}